// Round 6
// baseline (159.337 us; speedup 1.0000x reference)
//
#include <hip/hip_runtime.h>
#include <math.h>

#define N_STATES 32
#define N_TYPES 128
#define N_GENES 8192
#define N_SAMPLES 8192
#define LOG2PI_F 1.8378770664093453f

typedef float f32x4 __attribute__((ext_vector_type(4)));
typedef unsigned int u32x4 __attribute__((ext_vector_type(4)));

// round-to-nearest-even bf16 (upper 16 bits)
__device__ __forceinline__ unsigned int bf16r(float f) {
  unsigned int u = __builtin_bit_cast(unsigned int, f);
  return (u + 0x7FFFu + ((u >> 16) & 1u)) >> 16;
}

// ---------------- Kernel 1: packed per-(state,gene) table ----------------
// T[st,g] = bf16(mu) << 16 | bf16(1/sigma).  1 MB total -> L2-resident.
__global__ __launch_bounds__(256) void precompute_kernel(
    const float* __restrict__ cp, const float* __restrict__ Zmu,
    const float* __restrict__ Zs, unsigned int* __restrict__ T) {
  __shared__ float s_cp[N_TYPES], s_cp2[N_TYPES];
  const int st = blockIdx.y;
  const int g0 = blockIdx.x * 1024 + threadIdx.x * 4;

  if (threadIdx.x < N_TYPES) {
    float c = cp[st * N_TYPES + threadIdx.x];
    s_cp[threadIdx.x] = c;
    s_cp2[threadIdx.x] = c * c;
  }
  __syncthreads();

  float mu[4] = {0,0,0,0}, s13[4] = {0,0,0,0}, s2[4] = {0,0,0,0};
#pragma unroll 1
  for (int t = 0; t < N_TYPES; t += 4) {
    f32x4 zm[4], zs[4];
#pragma unroll
    for (int u = 0; u < 4; ++u) {
      zm[u] = *(const f32x4*)(Zmu + (size_t)(t + u) * N_GENES + g0);
      zs[u] = *(const f32x4*)(Zs  + (size_t)(t + u) * N_GENES + g0);
    }
#pragma unroll
    for (int u = 0; u < 4; ++u) {
      float c = s_cp[t + u], c2 = s_cp2[t + u];
#pragma unroll
      for (int j = 0; j < 4; ++j) {
        mu[j]  = fmaf(c, zm[u][j], mu[j]);
        s2[j]  = fmaf(c, zs[u][j], s2[j]);
        s13[j] = fmaf(c2, zs[u][j] * (1.f - zs[u][j]), s13[j]);
      }
    }
  }

  u32x4 pk;
#pragma unroll
  for (int j = 0; j < 4; ++j) {
    float sigma = s13[j] + s2[j] * s2[j];
    pk[j] = (bf16r(mu[j]) << 16) | bf16r(1.0f / sigma);
  }
  *(u32x4*)(T + (size_t)st * N_GENES + g0) = pk;
}

// ---------------- Kernel 2 helpers ----------------
__device__ __forceinline__ void issue_row(const float* __restrict__ Xr,
                                          const unsigned int* __restrict__ Tr,
                                          int tid, f32x4 (&xb)[8], u32x4 (&tb)[8]) {
  const f32x4* Xp = (const f32x4*)Xr + tid;
  const u32x4* Tp = (const u32x4*)Tr + tid;
#pragma unroll
  for (int it = 0; it < 8; ++it) xb[it] = Xp[it * 256];
#pragma unroll
  for (int it = 0; it < 8; ++it) tb[it] = Tp[it * 256];
  // pin VMEM issue order (VALU/SALU may cross, memory may not)
  __builtin_amdgcn_sched_barrier(0x6);
}

__device__ __forceinline__ float compute_row(float* __restrict__ outr,
                                             const f32x4 (&xb)[8],
                                             const u32x4 (&tb)[8]) {
  float acc = 0.f;
#pragma unroll
  for (int it = 0; it < 8; ++it) {
    f32x4 p;
#pragma unroll
    for (int j = 0; j < 4; ++j) {
      unsigned int tv = tb[it][j];
      float mu = __builtin_bit_cast(float, tv & 0xFFFF0000u);
      float iv = __builtin_bit_cast(float, tv << 16);
      float z = (xb[it][j] - mu) * iv;
      // logp = -0.5 z^2 - log(sigma) - 0.5 log(2pi);  log(sigma) = -log(inv)
      p[j] = fmaf(-0.5f * z, z, __logf(iv) - 0.5f * LOG2PI_F);
    }
    // single dwordx4 store at +1-shifted (4B-aligned) address
    float* oa = outr + it * 1024;
    asm volatile("global_store_dwordx4 %0, %1, off" : : "v"(oa), "v"(p) : "memory");
    acc += (p[0] + p[1]) + (p[2] + p[3]);
  }
  return acc;
}

// ---------------- Kernel 2: main, 4 rows/block, 2-buffer pipeline ----------------
// Aligned loads at gene 4k, store at out + row*NG + 4k + 1: the +1 output
// shift is absorbed by the store address -> no shuffles, no special lanes.
__global__ __launch_bounds__(256) void main_kernel(
    const float* __restrict__ X, const int* __restrict__ day,
    const unsigned int* __restrict__ T, float* __restrict__ out,
    float* __restrict__ partial) {
  const int row0 = blockIdx.x * 4;
  const int tid = threadIdx.x;

  const int st0 = day[row0] - 1, st1 = day[row0 + 1] - 1;
  const int st2 = day[row0 + 2] - 1, st3 = day[row0 + 3] - 1;
  const float* Xb = X + (size_t)row0 * N_GENES;
  float* ob = out + (size_t)row0 * N_GENES + 1 + tid * 4;

  f32x4 xa[8], xc[8];
  u32x4 ta[8], tc[8];
  float acc = 0.f;

  issue_row(Xb,               T + (size_t)st0 * N_GENES, tid, xa, ta);
  issue_row(Xb + N_GENES,     T + (size_t)st1 * N_GENES, tid, xc, tc);
  acc += compute_row(ob, xa, ta);
  issue_row(Xb + 2 * N_GENES, T + (size_t)st2 * N_GENES, tid, xa, ta);
  acc += compute_row(ob + N_GENES, xc, tc);
  issue_row(Xb + 3 * N_GENES, T + (size_t)st3 * N_GENES, tid, xc, tc);
  acc += compute_row(ob + 2 * N_GENES, xa, ta);
  acc += compute_row(ob + 3 * N_GENES, xc, tc);

#pragma unroll
  for (int off = 32; off; off >>= 1) acc += __shfl_down(acc, off, 64);
  __shared__ float s_w[4];
  int lane = threadIdx.x & 63, w = threadIdx.x >> 6;
  if (lane == 0) s_w[w] = acc;
  __syncthreads();
  if (threadIdx.x == 0)
    partial[blockIdx.x] = (s_w[0] + s_w[1]) + (s_w[2] + s_w[3]);
}

// ---------------- Kernel 3: final reduction (deterministic, double) ----------------
__global__ __launch_bounds__(256) void reduce_kernel(
    const float* __restrict__ partial, int n, float* __restrict__ out0) {
  double acc = 0.0;
  for (int i = threadIdx.x; i < n; i += 256) acc += (double)partial[i];
#pragma unroll
  for (int off = 32; off; off >>= 1) acc += __shfl_down(acc, off, 64);
  __shared__ double s_w[4];
  int lane = threadIdx.x & 63, w = threadIdx.x >> 6;
  if (lane == 0) s_w[w] = acc;
  __syncthreads();
  if (threadIdx.x == 0) out0[0] = (float)((s_w[0] + s_w[1]) + (s_w[2] + s_w[3]));
}

extern "C" void kernel_launch(void* const* d_in, const int* in_sizes, int n_in,
                              void* d_out, int out_size, void* d_ws, size_t ws_size,
                              hipStream_t stream) {
  const float* cp  = (const float*)d_in[0];   // (32,128)
  const float* Zmu = (const float*)d_in[1];   // (128,8192)
  const float* Zs  = (const float*)d_in[2];   // (128,8192)
  const float* X   = (const float*)d_in[3];   // (8192,8192)
  const int*   day = (const int*)d_in[4];     // (8192,)
  float* out = (float*)d_out;                 // [0]=sum, [1..]=logp flat
  float* ws  = (float*)d_ws;

  const int TBL = N_STATES * N_GENES;         // 262144
  unsigned int* T = (unsigned int*)ws;        // 1 MB packed table
  float* partial  = ws + TBL;

  dim3 g1(N_GENES / 1024, N_STATES);          // 8 x 32 = 256 blocks
  precompute_kernel<<<g1, 256, 0, stream>>>(cp, Zmu, Zs, T);

  const int NBLK = N_SAMPLES / 4;             // 2048 blocks, 4 rows each
  main_kernel<<<NBLK, 256, 0, stream>>>(X, day, T, out, partial);
  reduce_kernel<<<1, 256, 0, stream>>>(partial, NBLK, out);
}

// Round 7
// 137.852 us; speedup vs baseline: 1.1559x; 1.1559x over previous
//
#include <hip/hip_runtime.h>
#include <math.h>

#define N_STATES 32
#define N_TYPES 128
#define N_GENES 8192
#define N_SAMPLES 8192
#define N_TOT (N_SAMPLES * N_GENES)
#define LOG2PI_F 1.8378770664093453f

typedef float f32x4 __attribute__((ext_vector_type(4)));
typedef unsigned int u32x4 __attribute__((ext_vector_type(4)));

// round-to-nearest-even bf16 (upper 16 bits)
__device__ __forceinline__ unsigned int bf16r(float f) {
  unsigned int u = __builtin_bit_cast(unsigned int, f);
  return (u + 0x7FFFu + ((u >> 16) & 1u)) >> 16;
}

// logp from x and packed table entry (bf16 mu | bf16 inv)
__device__ __forceinline__ float logp_pk(float x, unsigned int tv) {
  float mu = __builtin_bit_cast(float, tv & 0xFFFF0000u);
  float iv = __builtin_bit_cast(float, tv << 16);
  float z = (x - mu) * iv;
  // logp = -0.5 z^2 - log(sigma) - 0.5 log(2pi);  log(sigma) = -log(inv)
  return fmaf(-0.5f * z, z, __logf(iv) - 0.5f * LOG2PI_F);
}

// ---------------- Kernel 1: packed per-(state,gene) table ----------------
// T[st,g] = bf16(mu) << 16 | bf16(1/sigma).  1 MB total -> L2-resident.
__global__ __launch_bounds__(256) void precompute_kernel(
    const float* __restrict__ cp, const float* __restrict__ Zmu,
    const float* __restrict__ Zs, unsigned int* __restrict__ T) {
  __shared__ float s_cp[N_TYPES], s_cp2[N_TYPES];
  const int st = blockIdx.y;
  const int g0 = blockIdx.x * 1024 + threadIdx.x * 4;

  if (threadIdx.x < N_TYPES) {
    float c = cp[st * N_TYPES + threadIdx.x];
    s_cp[threadIdx.x] = c;
    s_cp2[threadIdx.x] = c * c;
  }
  __syncthreads();

  float mu[4] = {0,0,0,0}, s13[4] = {0,0,0,0}, s2[4] = {0,0,0,0};
#pragma unroll 1
  for (int t = 0; t < N_TYPES; t += 4) {
    f32x4 zm[4], zs[4];
#pragma unroll
    for (int u = 0; u < 4; ++u) {
      zm[u] = *(const f32x4*)(Zmu + (size_t)(t + u) * N_GENES + g0);
      zs[u] = *(const f32x4*)(Zs  + (size_t)(t + u) * N_GENES + g0);
    }
#pragma unroll
    for (int u = 0; u < 4; ++u) {
      float c = s_cp[t + u], c2 = s_cp2[t + u];
#pragma unroll
      for (int j = 0; j < 4; ++j) {
        mu[j]  = fmaf(c, zm[u][j], mu[j]);
        s2[j]  = fmaf(c, zs[u][j], s2[j]);
        s13[j] = fmaf(c2, zs[u][j] * (1.f - zs[u][j]), s13[j]);
      }
    }
  }

  u32x4 pk;
#pragma unroll
  for (int j = 0; j < 4; ++j) {
    float sigma = s13[j] + s2[j] * s2[j];
    pk[j] = (bf16r(mu[j]) << 16) | bf16r(1.0f / sigma);
  }
  *(u32x4*)(T + (size_t)st * N_GENES + g0) = pk;
}

// ---------------- Kernel 2 helpers ----------------
// Batch-issue one row's 16 loads (8 X + 8 T), shifted -1 element (clamped at 0).
// memcpy -> 4B-aligned dwordx4 loads (gfx950 unaligned-access legal).
__device__ __forceinline__ void issue_row(const float* __restrict__ Xr,
                                          const unsigned int* __restrict__ Tr,
                                          int tid, f32x4 (&xb)[8], u32x4 (&tb)[8]) {
  const int base = 4 * tid - 1;
#pragma unroll
  for (int it = 0; it < 8; ++it) {
    int o = it * 1024 + base;
    if (o < 0) o = 0;                      // only (tid==0, it==0)
    __builtin_memcpy(&xb[it], Xr + o, 16);
  }
#pragma unroll
  for (int it = 0; it < 8; ++it) {
    int o = it * 1024 + base;
    if (o < 0) o = 0;
    __builtin_memcpy(&tb[it], Tr + o, 16);
  }
  __builtin_amdgcn_sched_barrier(0x6);     // pin load batch (VALU/SALU may cross)
}

// Compute one row; stores are ALIGNED dwordx4 at out[row*NG + 4c .. +3],
// holding logp[row*NG + 4c - 1 .. +2]  (the +1 output shift, absorbed by loads).
__device__ __forceinline__ float compute_row(
    int row, const float* __restrict__ X, const int* __restrict__ day,
    const unsigned int* __restrict__ T, float* __restrict__ out, int tid,
    const f32x4 (&xb)[8], const u32x4 (&tb)[8]) {
  float acc = 0.f;
  float* outr = out + (size_t)row * N_GENES + 4 * tid;
#pragma unroll
  for (int it = 0; it < 8; ++it) {
    f32x4 p;
#pragma unroll
    for (int j = 0; j < 4; ++j) p[j] = logp_pk(xb[it][j], tb[it][j]);
    if (it == 0 && tid == 0) {
      // clamped loads gave elements 0..3 of this row: shift lanes by 1
      p[3] = p[2]; p[2] = p[1]; p[1] = p[0];
      float p0 = 0.f;
      if (row > 0) {                       // e = row*NG - 1 (prev row, prev state)
        int stP = day[row - 1] - 1;
        p0 = logp_pk(X[(size_t)row * N_GENES - 1],
                     T[(size_t)stP * N_GENES + N_GENES - 1]);
      }
      p[0] = p0;                           // row 0: out[0] junk, reduce overwrites
    }
    __builtin_nontemporal_store(p, (f32x4*)(outr + it * 1024));
    acc += (p[0] + p[1]) + (p[2] + p[3]);
  }
  return acc;
}

// ---------------- Kernel 2: main, 4 rows/block, 2-buffer pipeline ----------------
__global__ __launch_bounds__(256) void main_kernel(
    const float* __restrict__ X, const int* __restrict__ day,
    const unsigned int* __restrict__ T, float* __restrict__ out,
    float* __restrict__ partial) {
  const int row0 = blockIdx.x * 4;
  const int tid = threadIdx.x;

  const int st0 = day[row0] - 1, st1 = day[row0 + 1] - 1;
  const int st2 = day[row0 + 2] - 1, st3 = day[row0 + 3] - 1;
  const float* Xb = X + (size_t)row0 * N_GENES;

  f32x4 xa[8], xc[8];
  u32x4 ta[8], tc[8];
  float acc = 0.f;

  issue_row(Xb,               T + (size_t)st0 * N_GENES, tid, xa, ta);
  issue_row(Xb + N_GENES,     T + (size_t)st1 * N_GENES, tid, xc, tc);
  acc += compute_row(row0,     X, day, T, out, tid, xa, ta);
  issue_row(Xb + 2 * N_GENES, T + (size_t)st2 * N_GENES, tid, xa, ta);
  acc += compute_row(row0 + 1, X, day, T, out, tid, xc, tc);
  issue_row(Xb + 3 * N_GENES, T + (size_t)st3 * N_GENES, tid, xc, tc);
  acc += compute_row(row0 + 2, X, day, T, out, tid, xa, ta);
  acc += compute_row(row0 + 3, X, day, T, out, tid, xc, tc);

  // last logp element (e = N_TOT-1) is owned by nobody's shifted window
  if (blockIdx.x == gridDim.x - 1 && tid == 255) {
    int st = day[N_SAMPLES - 1] - 1;
    float p = logp_pk(X[(size_t)N_TOT - 1],
                      T[(size_t)st * N_GENES + N_GENES - 1]);
    out[N_TOT] = p;
    acc += p;
  }

#pragma unroll
  for (int off = 32; off; off >>= 1) acc += __shfl_down(acc, off, 64);
  __shared__ float s_w[4];
  int lane = threadIdx.x & 63, w = threadIdx.x >> 6;
  if (lane == 0) s_w[w] = acc;
  __syncthreads();
  if (threadIdx.x == 0)
    partial[blockIdx.x] = (s_w[0] + s_w[1]) + (s_w[2] + s_w[3]);
}

// ---------------- Kernel 3: final reduction (deterministic, double) ----------------
__global__ __launch_bounds__(256) void reduce_kernel(
    const float* __restrict__ partial, int n, float* __restrict__ out0) {
  double acc = 0.0;
  for (int i = threadIdx.x; i < n; i += 256) acc += (double)partial[i];
#pragma unroll
  for (int off = 32; off; off >>= 1) acc += __shfl_down(acc, off, 64);
  __shared__ double s_w[4];
  int lane = threadIdx.x & 63, w = threadIdx.x >> 6;
  if (lane == 0) s_w[w] = acc;
  __syncthreads();
  if (threadIdx.x == 0) out0[0] = (float)((s_w[0] + s_w[1]) + (s_w[2] + s_w[3]));
}

extern "C" void kernel_launch(void* const* d_in, const int* in_sizes, int n_in,
                              void* d_out, int out_size, void* d_ws, size_t ws_size,
                              hipStream_t stream) {
  const float* cp  = (const float*)d_in[0];   // (32,128)
  const float* Zmu = (const float*)d_in[1];   // (128,8192)
  const float* Zs  = (const float*)d_in[2];   // (128,8192)
  const float* X   = (const float*)d_in[3];   // (8192,8192)
  const int*   day = (const int*)d_in[4];     // (8192,)
  float* out = (float*)d_out;                 // [0]=sum, [1..]=logp flat
  float* ws  = (float*)d_ws;

  const int TBL = N_STATES * N_GENES;         // 262144
  unsigned int* T = (unsigned int*)ws;        // 1 MB packed table
  float* partial  = ws + TBL;

  dim3 g1(N_GENES / 1024, N_STATES);          // 8 x 32 = 256 blocks
  precompute_kernel<<<g1, 256, 0, stream>>>(cp, Zmu, Zs, T);

  const int NBLK = N_SAMPLES / 4;             // 2048 blocks, 4 rows each
  main_kernel<<<NBLK, 256, 0, stream>>>(X, day, T, out, partial);
  reduce_kernel<<<1, 256, 0, stream>>>(partial, NBLK, out);
}

// Round 8
// 128.492 us; speedup vs baseline: 1.2401x; 1.0728x over previous
//
#include <hip/hip_runtime.h>
#include <math.h>

#define N_STATES 32
#define N_TYPES 128
#define N_GENES 8192
#define N_SAMPLES 8192
#define N_TOT (N_SAMPLES * N_GENES)
#define LOG2PI_F 1.8378770664093453f

typedef float f32x4 __attribute__((ext_vector_type(4)));
typedef unsigned int u32x4 __attribute__((ext_vector_type(4)));

// round-to-nearest-even bf16 (upper 16 bits)
__device__ __forceinline__ unsigned int bf16r(float f) {
  unsigned int u = __builtin_bit_cast(unsigned int, f);
  return (u + 0x7FFFu + ((u >> 16) & 1u)) >> 16;
}

// logp from x and packed table entry (bf16 mu | bf16 inv)
__device__ __forceinline__ float logp_pk(float x, unsigned int tv) {
  float mu = __builtin_bit_cast(float, tv & 0xFFFF0000u);
  float iv = __builtin_bit_cast(float, tv << 16);
  float z = (x - mu) * iv;
  // logp = -0.5 z^2 - log(sigma) - 0.5 log(2pi);  log(sigma) = -log(inv)
  return fmaf(-0.5f * z, z, __logf(iv) - 0.5f * LOG2PI_F);
}

// ---------------- Kernel 1: packed per-(state,gene) table ----------------
// T[st,g] = bf16(mu) << 16 | bf16(1/sigma).  1 MB total -> L2-resident.
__global__ __launch_bounds__(256) void precompute_kernel(
    const float* __restrict__ cp, const float* __restrict__ Zmu,
    const float* __restrict__ Zs, unsigned int* __restrict__ T) {
  __shared__ float s_cp[N_TYPES], s_cp2[N_TYPES];
  const int st = blockIdx.y;
  const int g0 = blockIdx.x * 1024 + threadIdx.x * 4;

  if (threadIdx.x < N_TYPES) {
    float c = cp[st * N_TYPES + threadIdx.x];
    s_cp[threadIdx.x] = c;
    s_cp2[threadIdx.x] = c * c;
  }
  __syncthreads();

  float mu[4] = {0,0,0,0}, s13[4] = {0,0,0,0}, s2[4] = {0,0,0,0};
#pragma unroll 1
  for (int t = 0; t < N_TYPES; t += 4) {
    f32x4 zm[4], zs[4];
#pragma unroll
    for (int u = 0; u < 4; ++u) {
      zm[u] = *(const f32x4*)(Zmu + (size_t)(t + u) * N_GENES + g0);
      zs[u] = *(const f32x4*)(Zs  + (size_t)(t + u) * N_GENES + g0);
    }
#pragma unroll
    for (int u = 0; u < 4; ++u) {
      float c = s_cp[t + u], c2 = s_cp2[t + u];
#pragma unroll
      for (int j = 0; j < 4; ++j) {
        mu[j]  = fmaf(c, zm[u][j], mu[j]);
        s2[j]  = fmaf(c, zs[u][j], s2[j]);
        s13[j] = fmaf(c2, zs[u][j] * (1.f - zs[u][j]), s13[j]);
      }
    }
  }

  u32x4 pk;
#pragma unroll
  for (int j = 0; j < 4; ++j) {
    float sigma = s13[j] + s2[j] * s2[j];
    pk[j] = (bf16r(mu[j]) << 16) | bf16r(1.0f / sigma);
  }
  *(u32x4*)(T + (size_t)st * N_GENES + g0) = pk;
}

// ---------------- Kernel 2: main. 1 row/block, 512 threads, depth-4 batch ----
// Loads shifted -1 element (clamped at 0) -> stores are ALIGNED f32x4:
// out[row*NG + 4c .. +3] holds logp[row*NG + 4c - 1 .. +2].
// Grid = 8192 blocks (4-8x oversubscribed per CU) for sustained occupancy.
__global__ __launch_bounds__(512) void main_kernel(
    const float* __restrict__ X, const int* __restrict__ day,
    const unsigned int* __restrict__ T, float* __restrict__ out,
    float* __restrict__ partial) {
  const int row = blockIdx.x;
  const int tid = threadIdx.x;
  const int st = day[row] - 1;                        // wave-uniform
  const float* Xr = X + (size_t)row * N_GENES;
  const unsigned int* Tr = T + (size_t)st * N_GENES;
  const int base = 4 * tid - 1;

  f32x4 xb[4];
  u32x4 tb[4];
#pragma unroll
  for (int it = 0; it < 4; ++it) {
    int o = it * 2048 + base;
    if (o < 0) o = 0;                                 // only (tid==0, it==0)
    __builtin_memcpy(&xb[it], Xr + o, 16);
  }
#pragma unroll
  for (int it = 0; it < 4; ++it) {
    int o = it * 2048 + base;
    if (o < 0) o = 0;
    __builtin_memcpy(&tb[it], Tr + o, 16);
  }
  __builtin_amdgcn_sched_barrier(0x6);                // pin load batch

  float acc = 0.f;
  float* outr = out + (size_t)row * N_GENES + 4 * tid;
#pragma unroll
  for (int it = 0; it < 4; ++it) {
    f32x4 p;
#pragma unroll
    for (int j = 0; j < 4; ++j) p[j] = logp_pk(xb[it][j], tb[it][j]);
    if (it == 0 && tid == 0) {
      // clamped loads gave elements 0..3 of this row: shift lanes by 1
      p[3] = p[2]; p[2] = p[1]; p[1] = p[0];
      float p0 = 0.f;
      if (row > 0) {                                  // logp[row*NG - 1]
        int stP = day[row - 1] - 1;
        p0 = logp_pk(X[(size_t)row * N_GENES - 1],
                     T[(size_t)stP * N_GENES + N_GENES - 1]);
      }
      p[0] = p0;                                      // row 0: junk, reduce fixes
    }
    __builtin_nontemporal_store(p, (f32x4*)(outr + it * 8192));
    acc += (p[0] + p[1]) + (p[2] + p[3]);
  }

  // last logp element (N_TOT-1) is outside every shifted window
  if (row == N_SAMPLES - 1 && tid == 511) {
    float p = logp_pk(X[(size_t)N_TOT - 1],
                      T[(size_t)st * N_GENES + N_GENES - 1]);
    out[N_TOT] = p;
    acc += p;
  }

#pragma unroll
  for (int off = 32; off; off >>= 1) acc += __shfl_down(acc, off, 64);
  __shared__ float s_w[8];
  int lane = tid & 63, w = tid >> 6;
  if (lane == 0) s_w[w] = acc;
  __syncthreads();
  if (tid == 0) {
    float s = 0.f;
#pragma unroll
    for (int i = 0; i < 8; ++i) s += s_w[i];
    partial[blockIdx.x] = s;
  }
}

// ---------------- Kernel 3: final reduction (deterministic, double) ----------------
__global__ __launch_bounds__(1024) void reduce_kernel(
    const float* __restrict__ partial, int n, float* __restrict__ out0) {
  double acc = 0.0;
  for (int i = threadIdx.x; i < n; i += 1024) acc += (double)partial[i];
#pragma unroll
  for (int off = 32; off; off >>= 1) acc += __shfl_down(acc, off, 64);
  __shared__ double s_w[16];
  int lane = threadIdx.x & 63, w = threadIdx.x >> 6;
  if (lane == 0) s_w[w] = acc;
  __syncthreads();
  if (threadIdx.x == 0) {
    double s = 0.0;
#pragma unroll
    for (int i = 0; i < 16; ++i) s += s_w[i];
    out0[0] = (float)s;
  }
}

extern "C" void kernel_launch(void* const* d_in, const int* in_sizes, int n_in,
                              void* d_out, int out_size, void* d_ws, size_t ws_size,
                              hipStream_t stream) {
  const float* cp  = (const float*)d_in[0];   // (32,128)
  const float* Zmu = (const float*)d_in[1];   // (128,8192)
  const float* Zs  = (const float*)d_in[2];   // (128,8192)
  const float* X   = (const float*)d_in[3];   // (8192,8192)
  const int*   day = (const int*)d_in[4];     // (8192,)
  float* out = (float*)d_out;                 // [0]=sum, [1..]=logp flat
  float* ws  = (float*)d_ws;

  const int TBL = N_STATES * N_GENES;         // 262144
  unsigned int* T = (unsigned int*)ws;        // 1 MB packed table
  float* partial  = ws + TBL;                 // 8192 floats

  dim3 g1(N_GENES / 1024, N_STATES);          // 8 x 32 = 256 blocks
  precompute_kernel<<<g1, 256, 0, stream>>>(cp, Zmu, Zs, T);

  main_kernel<<<N_SAMPLES, 512, 0, stream>>>(X, day, T, out, partial);
  reduce_kernel<<<1, 1024, 0, stream>>>(partial, N_SAMPLES, out);
}

// Round 9
// 127.542 us; speedup vs baseline: 1.2493x; 1.0074x over previous
//
#include <hip/hip_runtime.h>
#include <math.h>

#define N_STATES 32
#define N_TYPES 128
#define N_GENES 8192
#define N_SAMPLES 8192
#define N_TOT (N_SAMPLES * N_GENES)
#define LOG2PI_F 1.8378770664093453f

typedef float f32x2 __attribute__((ext_vector_type(2)));
typedef float f32x4 __attribute__((ext_vector_type(4)));
typedef unsigned int u32x2 __attribute__((ext_vector_type(2)));
typedef unsigned int u32x4 __attribute__((ext_vector_type(4)));

// round-to-nearest-even bf16 (upper 16 bits)
__device__ __forceinline__ unsigned int bf16r(float f) {
  unsigned int u = __builtin_bit_cast(unsigned int, f);
  return (u + 0x7FFFu + ((u >> 16) & 1u)) >> 16;
}

// logp from x and packed table entry (bf16 mu | bf16 inv)
__device__ __forceinline__ float logp_pk(float x, unsigned int tv) {
  float mu = __builtin_bit_cast(float, tv & 0xFFFF0000u);
  float iv = __builtin_bit_cast(float, tv << 16);
  float z = (x - mu) * iv;
  // logp = -0.5 z^2 - log(sigma) - 0.5 log(2pi);  log(sigma) = -log(inv)
  return fmaf(-0.5f * z, z, __logf(iv) - 0.5f * LOG2PI_F);
}

// ---------------- Kernel 1: packed per-(state,gene) table ----------------
// T[st,g] = bf16(mu)<<16 | bf16(1/sigma).  4 states/block, 512-gene chunks,
// 2 genes/thread: Z re-read 8x (was 32x), 128 blocks, ~5 us.
__global__ __launch_bounds__(256) void precompute_kernel(
    const float* __restrict__ cp, const float* __restrict__ Zmu,
    const float* __restrict__ Zs, unsigned int* __restrict__ T) {
  __shared__ float s_cp[4][N_TYPES], s_cp2[4][N_TYPES];
  const int st0 = blockIdx.y * 4;
  const int g0 = blockIdx.x * 512 + threadIdx.x * 2;

  for (int idx = threadIdx.x; idx < 4 * N_TYPES; idx += 256) {
    int s = idx >> 7, t = idx & (N_TYPES - 1);
    float c = cp[(st0 + s) * N_TYPES + t];
    s_cp[s][t] = c;
    s_cp2[s][t] = c * c;
  }
  __syncthreads();

  float mu[4][2] = {}, s2a[4][2] = {}, s13[4][2] = {};
#pragma unroll 1
  for (int t = 0; t < N_TYPES; t += 2) {
    f32x2 zm0 = *(const f32x2*)(Zmu + (size_t)t * N_GENES + g0);
    f32x2 zs0 = *(const f32x2*)(Zs  + (size_t)t * N_GENES + g0);
    f32x2 zm1 = *(const f32x2*)(Zmu + (size_t)(t + 1) * N_GENES + g0);
    f32x2 zs1 = *(const f32x2*)(Zs  + (size_t)(t + 1) * N_GENES + g0);
    f32x2 q0, q1;
#pragma unroll
    for (int j = 0; j < 2; ++j) {
      q0[j] = zs0[j] * (1.f - zs0[j]);
      q1[j] = zs1[j] * (1.f - zs1[j]);
    }
#pragma unroll
    for (int s = 0; s < 4; ++s) {
      float c0 = s_cp[s][t], c20 = s_cp2[s][t];
      float c1 = s_cp[s][t + 1], c21 = s_cp2[s][t + 1];
#pragma unroll
      for (int j = 0; j < 2; ++j) {
        mu[s][j]  = fmaf(c0, zm0[j], mu[s][j]);
        s2a[s][j] = fmaf(c0, zs0[j], s2a[s][j]);
        s13[s][j] = fmaf(c20, q0[j], s13[s][j]);
        mu[s][j]  = fmaf(c1, zm1[j], mu[s][j]);
        s2a[s][j] = fmaf(c1, zs1[j], s2a[s][j]);
        s13[s][j] = fmaf(c21, q1[j], s13[s][j]);
      }
    }
  }

#pragma unroll
  for (int s = 0; s < 4; ++s) {
    u32x2 pk;
#pragma unroll
    for (int j = 0; j < 2; ++j) {
      float sigma = s13[s][j] + s2a[s][j] * s2a[s][j];
      pk[j] = (bf16r(mu[s][j]) << 16) | bf16r(1.0f / sigma);
    }
    *(u32x2*)(T + (size_t)(st0 + s) * N_GENES + g0) = pk;
  }
}

// ---------------- Kernel 2: main. 1 row/block, 512 threads, depth-4 batch ----
// Loads shifted -1 element (clamped at 0) -> stores are ALIGNED f32x4:
// out[row*NG + 4c .. +3] holds logp[row*NG + 4c - 1 .. +2].
// Grid = 8192 blocks (4-8x oversubscribed per CU) for sustained occupancy.
__global__ __launch_bounds__(512) void main_kernel(
    const float* __restrict__ X, const int* __restrict__ day,
    const unsigned int* __restrict__ T, float* __restrict__ out,
    float* __restrict__ partial) {
  const int row = blockIdx.x;
  const int tid = threadIdx.x;
  const int st = day[row] - 1;                        // wave-uniform
  const float* Xr = X + (size_t)row * N_GENES;
  const unsigned int* Tr = T + (size_t)st * N_GENES;
  const int base = 4 * tid - 1;

  f32x4 xb[4];
  u32x4 tb[4];
#pragma unroll
  for (int it = 0; it < 4; ++it) {
    int o = it * 2048 + base;
    if (o < 0) o = 0;                                 // only (tid==0, it==0)
    __builtin_memcpy(&xb[it], Xr + o, 16);
  }
#pragma unroll
  for (int it = 0; it < 4; ++it) {
    int o = it * 2048 + base;
    if (o < 0) o = 0;
    __builtin_memcpy(&tb[it], Tr + o, 16);
  }
  __builtin_amdgcn_sched_barrier(0x6);                // pin load batch

  float acc = 0.f;
  float* outr = out + (size_t)row * N_GENES + 4 * tid;
#pragma unroll
  for (int it = 0; it < 4; ++it) {
    f32x4 p;
#pragma unroll
    for (int j = 0; j < 4; ++j) p[j] = logp_pk(xb[it][j], tb[it][j]);
    if (it == 0 && tid == 0) {
      // clamped loads gave elements 0..3 of this row: shift lanes by 1
      p[3] = p[2]; p[2] = p[1]; p[1] = p[0];
      float p0 = 0.f;
      if (row > 0) {                                  // logp[row*NG - 1]
        int stP = day[row - 1] - 1;
        p0 = logp_pk(X[(size_t)row * N_GENES - 1],
                     T[(size_t)stP * N_GENES + N_GENES - 1]);
      }
      p[0] = p0;                                      // row 0: junk, reduce fixes
    }
    __builtin_nontemporal_store(p, (f32x4*)(outr + it * 8192));
    acc += (p[0] + p[1]) + (p[2] + p[3]);
  }

  // last logp element (N_TOT-1) is outside every shifted window
  if (row == N_SAMPLES - 1 && tid == 511) {
    float p = logp_pk(X[(size_t)N_TOT - 1],
                      T[(size_t)st * N_GENES + N_GENES - 1]);
    out[N_TOT] = p;
    acc += p;
  }

#pragma unroll
  for (int off = 32; off; off >>= 1) acc += __shfl_down(acc, off, 64);
  __shared__ float s_w[8];
  int lane = tid & 63, w = tid >> 6;
  if (lane == 0) s_w[w] = acc;
  __syncthreads();
  if (tid == 0) {
    float s = 0.f;
#pragma unroll
    for (int i = 0; i < 8; ++i) s += s_w[i];
    partial[blockIdx.x] = s;
  }
}

// ---------------- Kernel 3: final reduction (deterministic, double) ----------------
__global__ __launch_bounds__(1024) void reduce_kernel(
    const float* __restrict__ partial, int n, float* __restrict__ out0) {
  double acc = 0.0;
  for (int i = threadIdx.x; i < n; i += 1024) acc += (double)partial[i];
#pragma unroll
  for (int off = 32; off; off >>= 1) acc += __shfl_down(acc, off, 64);
  __shared__ double s_w[16];
  int lane = threadIdx.x & 63, w = threadIdx.x >> 6;
  if (lane == 0) s_w[w] = acc;
  __syncthreads();
  if (threadIdx.x == 0) {
    double s = 0.0;
#pragma unroll
    for (int i = 0; i < 16; ++i) s += s_w[i];
    out0[0] = (float)s;
  }
}

extern "C" void kernel_launch(void* const* d_in, const int* in_sizes, int n_in,
                              void* d_out, int out_size, void* d_ws, size_t ws_size,
                              hipStream_t stream) {
  const float* cp  = (const float*)d_in[0];   // (32,128)
  const float* Zmu = (const float*)d_in[1];   // (128,8192)
  const float* Zs  = (const float*)d_in[2];   // (128,8192)
  const float* X   = (const float*)d_in[3];   // (8192,8192)
  const int*   day = (const int*)d_in[4];     // (8192,)
  float* out = (float*)d_out;                 // [0]=sum, [1..]=logp flat
  float* ws  = (float*)d_ws;

  const int TBL = N_STATES * N_GENES;         // 262144
  unsigned int* T = (unsigned int*)ws;        // 1 MB packed table
  float* partial  = ws + TBL;                 // 8192 floats

  dim3 g1(N_GENES / 512, N_STATES / 4);       // 16 x 8 = 128 blocks
  precompute_kernel<<<g1, 256, 0, stream>>>(cp, Zmu, Zs, T);

  main_kernel<<<N_SAMPLES, 512, 0, stream>>>(X, day, T, out, partial);
  reduce_kernel<<<1, 1024, 0, stream>>>(partial, N_SAMPLES, out);
}